// Round 3
// baseline (3393.291 us; speedup 1.0000x reference)
//
#include <hip/hip_runtime.h>
#include <math.h>

#define N_TOK 16384
#define DDIM  384
#define KCODE 8192
#define EMA   0.99f
#define EPS_F 1e-5f

// argmin tiling: 256 threads = 4 waves; wave owns 16 tokens (z wave-uniform),
// lane owns 4 codes of a 256-code chunk. acc[16][4] = 64 VGPRs.
#define BM 64        // tokens per block (4 waves x 16)
#define BN 256       // codes per chunk (64 lanes x 4)
#define DC 16        // d-chunk
#define KSPLIT 4     // code-range splits -> grid 256 x 4 = 1024 blocks
#define CSTRIDE 260  // 256 + 4 pad (1040B rows, 16B-aligned; writes 2-way, reads clean)

// ------- ws layout (float units) — identical footprint to R1/R2 -------
#define WS_COUNTS   16384
#define WS_EMBED    24576
#define WS_SUMSQ    3170304
#define WS_NACC     3170305
#define WS_CNORM    3170306
#define WS_PARTD    3178498
#define WS_PARTI    3244034

__global__ void cnorm_kernel(const float* __restrict__ cb, float* __restrict__ cnorm) {
    int wave = (blockIdx.x * blockDim.x + threadIdx.x) >> 6;
    int lane = threadIdx.x & 63;
    if (wave >= KCODE) return;
    const float* row = cb + wave * DDIM;
    float s = 0.f;
    #pragma unroll
    for (int r = 0; r < 6; r++) { float v = row[lane + 64 * r]; s += v * v; }
    #pragma unroll
    for (int off = 32; off > 0; off >>= 1) s += __shfl_down(s, off, 64);
    if (lane == 0) cnorm[wave] = s;
}

__launch_bounds__(256)
__global__ void argmin_kernel(const float* __restrict__ z, const float* __restrict__ cb,
                              const float* __restrict__ cnorm,
                              float* __restrict__ part_d, int* __restrict__ part_i) {
    __shared__ float cs[DC * CSTRIDE];   // 16.6 KB; codes transposed cs[d][n]

    const int tid  = threadIdx.x;
    const int lane = tid & 63;
    const int wv   = __builtin_amdgcn_readfirstlane(tid >> 6);  // wave id, forced uniform
    const int m0   = blockIdx.x * BM;
    const int zrow0 = m0 + wv * 16;      // this wave's 16 tokens (uniform)
    const int ks = blockIdx.y;
    const int k_begin = ks * (KCODE / KSPLIT);
    const int k_end   = k_begin + (KCODE / KSPLIT);

    // staging mapping: thread handles one float4 of one code row per r-iter
    const int srow = tid >> 2;           // 0..63 (+ r*64): code row within chunk
    const int sp   = tid & 3;            // which float4 (4 dims) of the 16-dim chunk

    float best[16];
    int   besti[16];
    #pragma unroll
    for (int t = 0; t < 16; t++) { best[t] = 3.4e38f; besti[t] = 0; }

    for (int kc = k_begin; kc < k_end; kc += BN) {
        float acc[16][4];
        #pragma unroll
        for (int t = 0; t < 16; t++)
            #pragma unroll
            for (int e = 0; e < 4; e++) acc[t][e] = 0.f;

        for (int dc = 0; dc < DDIM; dc += DC) {
            // stage 256 codes x 16 dims, transposed. Writes: banks 2-way aliased = free.
            #pragma unroll
            for (int r = 0; r < 4; r++) {
                int row = srow + r * 64;
                const float4 v = *reinterpret_cast<const float4*>(
                    cb + (size_t)(kc + row) * DDIM + dc + sp * 4);
                cs[(sp * 4 + 0) * CSTRIDE + row] = v.x;
                cs[(sp * 4 + 1) * CSTRIDE + row] = v.y;
                cs[(sp * 4 + 2) * CSTRIDE + row] = v.z;
                cs[(sp * 4 + 3) * CSTRIDE + row] = v.w;
            }
            __syncthreads();

            #pragma unroll
            for (int d2 = 0; d2 < DC / 2; d2++) {
                // wave-uniform z loads (scalar-cache path): 16 tokens x 2 dims
                float2 zq[16];
                #pragma unroll
                for (int t = 0; t < 16; t++)
                    zq[t] = *reinterpret_cast<const float2*>(
                        z + (size_t)(zrow0 + t) * DDIM + dc + d2 * 2);
                #pragma unroll
                for (int dd = 0; dd < 2; dd++) {
                    const float4 cv = *reinterpret_cast<const float4*>(
                        cs + (d2 * 2 + dd) * CSTRIDE + lane * 4);   // conflict-free b128
                    #pragma unroll
                    for (int t = 0; t < 16; t++) {
                        const float zv = dd ? zq[t].y : zq[t].x;
                        acc[t][0] = fmaf(zv, cv.x, acc[t][0]);
                        acc[t][1] = fmaf(zv, cv.y, acc[t][1]);
                        acc[t][2] = fmaf(zv, cv.z, acc[t][2]);
                        acc[t][3] = fmaf(zv, cv.w, acc[t][3]);
                    }
                }
            }
            __syncthreads();
        }

        // epilogue: dist = ||c||^2 - 2 z.c ; lane's 4 codes are kc + lane*4 + e
        const float4 cn = *reinterpret_cast<const float4*>(cnorm + kc + lane * 4);
        const float cnv[4] = {cn.x, cn.y, cn.z, cn.w};
        #pragma unroll
        for (int e = 0; e < 4; e++) {
            const int id = kc + lane * 4 + e;
            #pragma unroll
            for (int t = 0; t < 16; t++) {
                float dist = cnv[e] - 2.f * acc[t][e];
                if (dist < best[t] || (dist == best[t] && id < besti[t])) {
                    best[t] = dist; besti[t] = id;
                }
            }
        }
    }

    // per-token min across the 64 lanes (each lane covered its own code columns)
    #pragma unroll
    for (int t = 0; t < 16; t++) {
        float bd = best[t];
        int   bi = besti[t];
        #pragma unroll
        for (int off = 32; off > 0; off >>= 1) {
            float od = __shfl_xor(bd, off, 64);
            int   oi = __shfl_xor(bi, off, 64);
            if (od < bd || (od == bd && oi < bi)) { bd = od; bi = oi; }
        }
        if (lane == 0) {
            int m = zrow0 + t;
            part_d[(size_t)m * KSPLIT + ks] = bd;
            part_i[(size_t)m * KSPLIT + ks] = bi;
        }
    }
}

__global__ void merge_kernel(const float* __restrict__ pd, const int* __restrict__ pi,
                             int* __restrict__ ws_idx, float* __restrict__ out_idx) {
    int t = blockIdx.x * blockDim.x + threadIdx.x;
    if (t >= N_TOK) return;
    float bd = pd[t * KSPLIT];
    int   bi = pi[t * KSPLIT];
    #pragma unroll
    for (int x = 1; x < KSPLIT; x++) {
        float dd = pd[t * KSPLIT + x];
        int   ii = pi[t * KSPLIT + x];
        if (dd < bd || (dd == bd && ii < bi)) { bd = dd; bi = ii; }
    }
    ws_idx[t] = bi;
    out_idx[t] = (float)bi;
}

// one wave per token: gather quantized, accumulate loss, scatter EMA stats
__global__ void gather_scatter_kernel(const float* __restrict__ z, const float* __restrict__ cb,
                                      const int* __restrict__ ws_idx,
                                      float* __restrict__ out_q, float* __restrict__ embed_ws,
                                      float* __restrict__ counts, float* __restrict__ sumsq) {
    int t = (blockIdx.x * blockDim.x + threadIdx.x) >> 6;
    int lane = threadIdx.x & 63;
    if (t >= N_TOK) return;
    int k = ws_idx[t];
    const float* zr = z + (size_t)t * DDIM;
    const float* cr = cb + (size_t)k * DDIM;
    float* qr = out_q + (size_t)t * DDIM;
    float* er = embed_ws + (size_t)k * DDIM;
    float s = 0.f;
    #pragma unroll
    for (int r = 0; r < 6; r++) {
        int d = lane + 64 * r;
        float zv = zr[d];
        float qv = cr[d];
        qr[d] = qv;
        float df = zv - qv;
        s += df * df;
        atomicAdd(er + d, zv);
    }
    #pragma unroll
    for (int off = 32; off > 0; off >>= 1) s += __shfl_down(s, off, 64);
    if (lane == 0) {
        atomicAdd(sumsq, s);
        atomicAdd(counts + k, 1.0f);
    }
}

__global__ void cluster_kernel(const float* __restrict__ ema_cs, const float* __restrict__ counts,
                               float* __restrict__ out_ncs, float* __restrict__ n_acc,
                               const float* __restrict__ sumsq, float* __restrict__ out_loss) {
    int i = blockIdx.x * blockDim.x + threadIdx.x;
    float v = 0.f;
    if (i < KCODE) {
        v = EMA * ema_cs[i] + (1.f - EMA) * counts[i];
        out_ncs[i] = v;
    }
    __shared__ float sm[4];
    int lane = threadIdx.x & 63, w = threadIdx.x >> 6;
    #pragma unroll
    for (int off = 32; off > 0; off >>= 1) v += __shfl_down(v, off, 64);
    if (lane == 0) sm[w] = v;
    __syncthreads();
    if (threadIdx.x == 0) {
        atomicAdd(n_acc, sm[0] + sm[1] + sm[2] + sm[3]);
        if (blockIdx.x == 0) {
            out_loss[0] = 1.25f * sumsq[0] / (float)(N_TOK * DDIM);
        }
    }
}

__global__ void codebook_kernel(const float* __restrict__ ema_es, const float* __restrict__ embed_ws,
                                const float* __restrict__ ncs, const float* __restrict__ n_acc,
                                float* __restrict__ out_es, float* __restrict__ out_cb) {
    int i = blockIdx.x * blockDim.x + threadIdx.x;
    if (i >= KCODE * DDIM) return;
    float es = EMA * ema_es[i] + (1.f - EMA) * embed_ws[i];
    out_es[i] = es;
    int k = i / DDIM;
    float n = n_acc[0];
    float smooth = (ncs[k] + EPS_F) / (n + (float)KCODE * EPS_F) * n;
    out_cb[i] = es / smooth;
}

extern "C" void kernel_launch(void* const* d_in, const int* in_sizes, int n_in,
                              void* d_out, int out_size, void* d_ws, size_t ws_size,
                              hipStream_t stream) {
    const float* z       = (const float*)d_in[0];
    const float* cb      = (const float*)d_in[1];
    const float* ema_cs  = (const float*)d_in[2];
    const float* ema_es  = (const float*)d_in[3];

    float* out      = (float*)d_out;
    float* out_q    = out;                       // 6291456
    float* out_idx  = out + 6291456;             // 16384
    float* out_loss = out + 6307840;             // 1
    float* out_ncs  = out + 6307841;             // 8192
    float* out_es   = out + 6316033;             // 3145728
    float* out_cb   = out + 9461761;             // 3145728

    float* ws      = (float*)d_ws;
    int*   ws_idx  = (int*)ws;
    float* counts  = ws + WS_COUNTS;
    float* embed   = ws + WS_EMBED;
    float* sumsq   = ws + WS_SUMSQ;
    float* n_acc   = ws + WS_NACC;
    float* cnorm   = ws + WS_CNORM;
    float* part_d  = ws + WS_PARTD;
    int*   part_i  = (int*)(ws + WS_PARTI);

    hipMemsetAsync(counts, 0, (size_t)(WS_CNORM - WS_COUNTS) * sizeof(float), stream);

    cnorm_kernel<<<KCODE * 64 / 256, 256, 0, stream>>>(cb, cnorm);
    dim3 grid_am(N_TOK / BM, KSPLIT, 1);
    argmin_kernel<<<grid_am, 256, 0, stream>>>(z, cb, cnorm, part_d, part_i);
    merge_kernel<<<N_TOK / 256, 256, 0, stream>>>(part_d, part_i, ws_idx, out_idx);
    gather_scatter_kernel<<<N_TOK * 64 / 256, 256, 0, stream>>>(z, cb, ws_idx, out_q, embed, counts, sumsq);
    cluster_kernel<<<(KCODE + 255) / 256, 256, 0, stream>>>(ema_cs, counts, out_ncs, n_acc, sumsq, out_loss);
    codebook_kernel<<<(KCODE * DDIM) / 256, 256, 0, stream>>>(ema_es, embed, out_ncs, n_acc, out_es, out_cb);
}

// Round 4
// 745.372 us; speedup vs baseline: 4.5525x; 4.5525x over previous
//
#include <hip/hip_runtime.h>
#include <math.h>

#define N_TOK 16384
#define DDIM  384
#define KCODE 8192
#define EMA   0.99f
#define EPS_F 1e-5f
#define MARGIN 0.5f
#define NB 32            // KCODE / 256 code-blocks in coarse pass

typedef _Float16 f16x8 __attribute__((ext_vector_type(8)));
typedef float    f32x4 __attribute__((ext_vector_type(4)));

// ---- ws byte offsets (total 12,681,472 B <= proven 13,041,672 B from R1) ----
// Region A [0, 12582912): phase1 = partials/cnorm/flags, phase2 = embed accum
#define OFF_PD1    0UL        // [NB][N_TOK] f32 coarse best dist
#define OFF_PI1    2097152UL  // [NB][N_TOK] i32 coarse best idx
#define OFF_PD2    4194304UL  // [NB][N_TOK] f32 coarse 2nd dist
#define OFF_PRD    6291456UL  // [16][N_TOK] f32 rescore best dist
#define OFF_PRI    7340032UL  // [16][N_TOK] i32 rescore best idx
#define OFF_CNORM  8388608UL  // [KCODE] f32
#define OFF_FLIST  8421376UL  // [N_TOK] i32 flagged tokens
#define OFF_FCNT   8486912UL  // i32 + pad
#define OFF_EMBED  0UL        // phase2: [KCODE*DDIM] f32
// outside region A:
#define OFF_WSIDX  12582912UL // [N_TOK] i32
#define OFF_COUNTS 12648448UL // [KCODE] f32
#define OFF_SUMSQ  12681216UL // f32
#define OFF_NACC   12681220UL // f32

__global__ void cnorm_kernel(const float* __restrict__ cb, float* __restrict__ cnorm) {
    int wave = (blockIdx.x * blockDim.x + threadIdx.x) >> 6;
    int lane = threadIdx.x & 63;
    if (wave >= KCODE) return;
    const float* row = cb + (size_t)wave * DDIM;
    float s = 0.f;
    #pragma unroll
    for (int r = 0; r < 6; r++) { float v = row[lane + 64 * r]; s += v * v; }
    #pragma unroll
    for (int off = 32; off > 0; off >>= 1) s += __shfl_down(s, off, 64);
    if (lane == 0) cnorm[wave] = s;
}

// ---- coarse pass: f16 MFMA GEMM (z . c^T) with per-token top-2 over 256-code blocks ----
// block = 512 threads = 8 waves (wy in {0,1} token-half, wx in {0..3} code-quarter)
// tile 128 tokens x 256 codes, BK=32, 12 K-iters
__launch_bounds__(512)
__global__ void argmin16_kernel(const float* __restrict__ z, const float* __restrict__ cb,
                                const float* __restrict__ cnorm,
                                float* __restrict__ pd1, int* __restrict__ pi1,
                                float* __restrict__ pd2) {
    __shared__ _Float16 As[128 * 32];   // 8 KB, rows 64B (b128-aligned frags)
    __shared__ _Float16 Bs[256 * 32];   // 16 KB
    __shared__ float xd1[128 * 4];
    __shared__ float xd2[128 * 4];
    __shared__ int   xi1[128 * 4];

    const int tid  = threadIdx.x;
    const int lane = tid & 63;
    const int wv   = tid >> 6;
    const int wy   = wv >> 2;
    const int wx   = wv & 3;
    const int m0   = blockIdx.x * 128;
    const int n0   = blockIdx.y * 256;
    const int l15  = lane & 15;
    const int l4   = lane >> 4;

    f32x4 acc[4][4];
    #pragma unroll
    for (int i = 0; i < 4; i++)
        #pragma unroll
        for (int j = 0; j < 4; j++) acc[i][j] = (f32x4){0.f, 0.f, 0.f, 0.f};

    const int arow = tid >> 2, ac4 = tid & 3;

    for (int kc = 0; kc < DDIM; kc += 32) {
        { // stage A tile: convert fp32 -> f16 in flight
            const float* s = z + (size_t)(m0 + arow) * DDIM + kc + ac4 * 8;
            float4 v0 = *(const float4*)(s);
            float4 v1 = *(const float4*)(s + 4);
            f16x8 h;
            h[0]=(_Float16)v0.x; h[1]=(_Float16)v0.y; h[2]=(_Float16)v0.z; h[3]=(_Float16)v0.w;
            h[4]=(_Float16)v1.x; h[5]=(_Float16)v1.y; h[6]=(_Float16)v1.z; h[7]=(_Float16)v1.w;
            *(f16x8*)(As + arow * 32 + ac4 * 8) = h;
        }
        #pragma unroll
        for (int r = 0; r < 2; r++) { // stage B tile
            int q = tid + r * 512;
            int row = q >> 2, c4 = q & 3;
            const float* s = cb + (size_t)(n0 + row) * DDIM + kc + c4 * 8;
            float4 v0 = *(const float4*)(s);
            float4 v1 = *(const float4*)(s + 4);
            f16x8 h;
            h[0]=(_Float16)v0.x; h[1]=(_Float16)v0.y; h[2]=(_Float16)v0.z; h[3]=(_Float16)v0.w;
            h[4]=(_Float16)v1.x; h[5]=(_Float16)v1.y; h[6]=(_Float16)v1.z; h[7]=(_Float16)v1.w;
            *(f16x8*)(Bs + row * 32 + c4 * 8) = h;
        }
        __syncthreads();
        f16x8 af[4], bf[4];
        #pragma unroll
        for (int im = 0; im < 4; im++)
            af[im] = *(const f16x8*)(As + (wy * 64 + im * 16 + l15) * 32 + l4 * 8);
        #pragma unroll
        for (int in = 0; in < 4; in++)
            bf[in] = *(const f16x8*)(Bs + (wx * 64 + in * 16 + l15) * 32 + l4 * 8);
        #pragma unroll
        for (int im = 0; im < 4; im++)
            #pragma unroll
            for (int in = 0; in < 4; in++)
                acc[im][in] = __builtin_amdgcn_mfma_f32_16x16x32_f16(af[im], bf[in], acc[im][in], 0, 0, 0);
        __syncthreads();
    }

    // epilogue: dist = ||c||^2 - 2 z.c ; per-token top-2.
    // C/D layout: col(code)=lane&15, row(token)=(lane>>4)*4+reg
    float cn[4]; int cid[4];
    #pragma unroll
    for (int in = 0; in < 4; in++) {
        cid[in] = n0 + wx * 64 + in * 16 + l15;
        cn[in] = cnorm[cid[in]];
    }
    #pragma unroll
    for (int im = 0; im < 4; im++) {
        #pragma unroll
        for (int reg = 0; reg < 4; reg++) {
            float d1 = cn[0] - 2.f * acc[im][0][reg];
            int   i1 = cid[0];
            float d2 = 3.4e38f;
            #pragma unroll
            for (int in = 1; in < 4; in++) {
                float dd = cn[in] - 2.f * acc[im][in][reg];
                if (dd < d1) { d2 = d1; d1 = dd; i1 = cid[in]; }
                else d2 = fminf(d2, dd);
            }
            #pragma unroll
            for (int off = 1; off < 16; off <<= 1) {
                float od1 = __shfl_xor(d1, off, 16);
                int   oi1 = __shfl_xor(i1, off, 16);
                float od2 = __shfl_xor(d2, off, 16);
                if (od1 < d1 || (od1 == d1 && oi1 < i1)) { d2 = fminf(d1, od2); d1 = od1; i1 = oi1; }
                else d2 = fminf(d2, od1);
            }
            if (l15 == 0) {
                int tl = wy * 64 + im * 16 + l4 * 4 + reg;
                xd1[tl * 4 + wx] = d1; xi1[tl * 4 + wx] = i1; xd2[tl * 4 + wx] = d2;
            }
        }
    }
    __syncthreads();
    if (tid < 128) {
        float d1 = xd1[tid * 4], d2 = xd2[tid * 4];
        int   i1 = xi1[tid * 4];
        #pragma unroll
        for (int x = 1; x < 4; x++) {
            float od1 = xd1[tid * 4 + x], od2 = xd2[tid * 4 + x];
            int   oi1 = xi1[tid * 4 + x];
            if (od1 < d1 || (od1 == d1 && oi1 < i1)) { d2 = fminf(d1, od2); d1 = od1; i1 = oi1; }
            else d2 = fminf(d2, od1);
        }
        size_t o = (size_t)blockIdx.y * N_TOK + m0 + tid;
        pd1[o] = d1; pi1[o] = i1; pd2[o] = d2;
    }
}

// merge 32 coarse partials per token; flag near-ties (gap < MARGIN) for exact rescore
__global__ void topmerge_kernel(const float* __restrict__ pd1, const int* __restrict__ pi1,
                                const float* __restrict__ pd2,
                                int* __restrict__ ws_idx, float* __restrict__ out_idx,
                                int* __restrict__ fcnt, int* __restrict__ flist) {
    int t = blockIdx.x * blockDim.x + threadIdx.x;
    if (t >= N_TOK) return;
    float d1 = pd1[t], d2 = pd2[t];
    int   i1 = pi1[t];
    for (int nb = 1; nb < NB; nb++) {
        size_t o = (size_t)nb * N_TOK + t;
        float od1 = pd1[o], od2 = pd2[o];
        int   oi1 = pi1[o];
        if (od1 < d1 || (od1 == d1 && oi1 < i1)) { d2 = fminf(d1, od2); d1 = od1; i1 = oi1; }
        else d2 = fminf(d2, od1);
    }
    ws_idx[t] = i1;
    out_idx[t] = (float)i1;
    if (d2 - d1 < MARGIN) {
        int s = atomicAdd(fcnt, 1);
        flist[s] = t;
    }
}

// exact fp32 rescore of flagged tokens: 16 code-splits x groups of 8 tokens
__launch_bounds__(256)
__global__ void rescore_kernel(const float* __restrict__ z, const float* __restrict__ cb,
                               const float* __restrict__ cnorm,
                               const int* __restrict__ flist, const int* __restrict__ fcnt,
                               float* __restrict__ prd, int* __restrict__ pri) {
    __shared__ float zt[8 * 384];
    __shared__ float rd[8 * 4];
    __shared__ int   ri[8 * 4];
    const int tid = threadIdx.x;
    const int lane = tid & 63, wv = tid >> 6;
    const int s = blockIdx.x;
    const int count = fcnt[0];
    for (int g = blockIdx.y; g * 8 < count; g += 256) {
        #pragma unroll
        for (int r = 0; r < 3; r++) {
            int q = tid + r * 256;
            int j = q / 96, d4 = q % 96;
            int slot = g * 8 + j; if (slot >= count) slot = count - 1;
            int tok = flist[slot];
            *(float4*)(zt + j * 384 + d4 * 4) = *(const float4*)(z + (size_t)tok * DDIM + d4 * 4);
        }
        __syncthreads();
        float bd[8]; int bi[8];
        #pragma unroll
        for (int j = 0; j < 8; j++) { bd[j] = 3.4e38f; bi[j] = 0; }
        #pragma unroll
        for (int cc = 0; cc < 2; cc++) {
            int c = s * 512 + cc * 256 + tid;
            const float* cr = cb + (size_t)c * DDIM;
            float a[8];
            #pragma unroll
            for (int j = 0; j < 8; j++) a[j] = 0.f;
            for (int d4 = 0; d4 < 96; d4++) {
                float4 cv = *(const float4*)(cr + d4 * 4);
                #pragma unroll
                for (int j = 0; j < 8; j++) {
                    float4 zv = *(const float4*)(zt + j * 384 + d4 * 4);
                    a[j] = fmaf(zv.x, cv.x, a[j]);
                    a[j] = fmaf(zv.y, cv.y, a[j]);
                    a[j] = fmaf(zv.z, cv.z, a[j]);
                    a[j] = fmaf(zv.w, cv.w, a[j]);
                }
            }
            float cnv = cnorm[c];
            #pragma unroll
            for (int j = 0; j < 8; j++) {
                float dd = cnv - 2.f * a[j];
                if (dd < bd[j]) { bd[j] = dd; bi[j] = c; }
            }
        }
        #pragma unroll
        for (int j = 0; j < 8; j++) {
            float d = bd[j]; int i = bi[j];
            #pragma unroll
            for (int off = 32; off > 0; off >>= 1) {
                float od = __shfl_xor(d, off, 64);
                int   oi = __shfl_xor(i, off, 64);
                if (od < d || (od == d && oi < i)) { d = od; i = oi; }
            }
            if (lane == 0) { rd[j * 4 + wv] = d; ri[j * 4 + wv] = i; }
        }
        __syncthreads();
        if (tid < 8) {
            float d = rd[tid * 4]; int i = ri[tid * 4];
            #pragma unroll
            for (int x = 1; x < 4; x++) {
                float od = rd[tid * 4 + x]; int oi = ri[tid * 4 + x];
                if (od < d || (od == d && oi < i)) { d = od; i = oi; }
            }
            int slot = g * 8 + tid; if (slot >= count) slot = count - 1;
            int tok = flist[slot];
            prd[(size_t)s * N_TOK + tok] = d;
            pri[(size_t)s * N_TOK + tok] = i;
        }
        __syncthreads();
    }
}

__global__ void rsmerge_kernel(const float* __restrict__ prd, const int* __restrict__ pri,
                               const int* __restrict__ flist, const int* __restrict__ fcnt,
                               int* __restrict__ ws_idx, float* __restrict__ out_idx) {
    int slot = blockIdx.x * blockDim.x + threadIdx.x;
    if (slot >= fcnt[0]) return;
    int tok = flist[slot];
    float d = prd[tok]; int i = pri[tok];
    for (int s = 1; s < 16; s++) {
        float od = prd[(size_t)s * N_TOK + tok];
        int   oi = pri[(size_t)s * N_TOK + tok];
        if (od < d || (od == d && oi < i)) { d = od; i = oi; }
    }
    ws_idx[tok] = i;
    out_idx[tok] = (float)i;
}

__global__ void gather_scatter_kernel(const float* __restrict__ z, const float* __restrict__ cb,
                                      const int* __restrict__ ws_idx,
                                      float* __restrict__ out_q, float* __restrict__ embed_ws,
                                      float* __restrict__ counts, float* __restrict__ sumsq) {
    int t = (blockIdx.x * blockDim.x + threadIdx.x) >> 6;
    int lane = threadIdx.x & 63;
    if (t >= N_TOK) return;
    int k = ws_idx[t];
    const float* zr = z + (size_t)t * DDIM;
    const float* cr = cb + (size_t)k * DDIM;
    float* qr = out_q + (size_t)t * DDIM;
    float* er = embed_ws + (size_t)k * DDIM;
    float s = 0.f;
    #pragma unroll
    for (int r = 0; r < 6; r++) {
        int d = lane + 64 * r;
        float zv = zr[d];
        float qv = cr[d];
        qr[d] = qv;
        float df = zv - qv;
        s += df * df;
        atomicAdd(er + d, zv);
    }
    #pragma unroll
    for (int off = 32; off > 0; off >>= 1) s += __shfl_down(s, off, 64);
    if (lane == 0) {
        atomicAdd(sumsq, s);
        atomicAdd(counts + k, 1.0f);
    }
}

__global__ void cluster_kernel(const float* __restrict__ ema_cs, const float* __restrict__ counts,
                               float* __restrict__ out_ncs, float* __restrict__ n_acc,
                               const float* __restrict__ sumsq, float* __restrict__ out_loss) {
    int i = blockIdx.x * blockDim.x + threadIdx.x;
    float v = 0.f;
    if (i < KCODE) {
        v = EMA * ema_cs[i] + (1.f - EMA) * counts[i];
        out_ncs[i] = v;
    }
    __shared__ float sm[4];
    int lane = threadIdx.x & 63, w = threadIdx.x >> 6;
    #pragma unroll
    for (int off = 32; off > 0; off >>= 1) v += __shfl_down(v, off, 64);
    if (lane == 0) sm[w] = v;
    __syncthreads();
    if (threadIdx.x == 0) {
        atomicAdd(n_acc, sm[0] + sm[1] + sm[2] + sm[3]);
        if (blockIdx.x == 0) {
            out_loss[0] = 1.25f * sumsq[0] / (float)(N_TOK * DDIM);
        }
    }
}

__global__ void codebook_kernel(const float* __restrict__ ema_es, const float* __restrict__ embed_ws,
                                const float* __restrict__ ncs, const float* __restrict__ n_acc,
                                float* __restrict__ out_es, float* __restrict__ out_cb) {
    int i = blockIdx.x * blockDim.x + threadIdx.x;
    if (i >= KCODE * DDIM) return;
    float es = EMA * ema_es[i] + (1.f - EMA) * embed_ws[i];
    out_es[i] = es;
    int k = i / DDIM;
    float n = n_acc[0];
    float smooth = (ncs[k] + EPS_F) / (n + (float)KCODE * EPS_F) * n;
    out_cb[i] = es / smooth;
}

extern "C" void kernel_launch(void* const* d_in, const int* in_sizes, int n_in,
                              void* d_out, int out_size, void* d_ws, size_t ws_size,
                              hipStream_t stream) {
    const float* z       = (const float*)d_in[0];
    const float* cb      = (const float*)d_in[1];
    const float* ema_cs  = (const float*)d_in[2];
    const float* ema_es  = (const float*)d_in[3];

    float* out      = (float*)d_out;
    float* out_q    = out;
    float* out_idx  = out + 6291456;
    float* out_loss = out + 6307840;
    float* out_ncs  = out + 6307841;
    float* out_es   = out + 6316033;
    float* out_cb   = out + 9461761;

    char* w = (char*)d_ws;
    float* pd1    = (float*)(w + OFF_PD1);
    int*   pi1    = (int*)  (w + OFF_PI1);
    float* pd2    = (float*)(w + OFF_PD2);
    float* prd    = (float*)(w + OFF_PRD);
    int*   pri    = (int*)  (w + OFF_PRI);
    float* cnorm  = (float*)(w + OFF_CNORM);
    int*   flist  = (int*)  (w + OFF_FLIST);
    int*   fcnt   = (int*)  (w + OFF_FCNT);
    float* embed  = (float*)(w + OFF_EMBED);
    int*   ws_idx = (int*)  (w + OFF_WSIDX);
    float* counts = (float*)(w + OFF_COUNTS);
    float* sumsq  = (float*)(w + OFF_SUMSQ);
    float* n_acc  = (float*)(w + OFF_NACC);

    hipMemsetAsync(w + OFF_FCNT, 0, 256, stream);
    hipMemsetAsync(w + OFF_COUNTS, 0, 32768 + 256, stream);  // counts + sumsq + n_acc

    cnorm_kernel<<<KCODE * 64 / 256, 256, 0, stream>>>(cb, cnorm);

    dim3 grid_am(N_TOK / 128, KCODE / 256, 1);
    argmin16_kernel<<<grid_am, 512, 0, stream>>>(z, cb, cnorm, pd1, pi1, pd2);

    topmerge_kernel<<<N_TOK / 256, 256, 0, stream>>>(pd1, pi1, pd2, ws_idx, out_idx, fcnt, flist);

    dim3 grid_rs(16, 256, 1);
    rescore_kernel<<<grid_rs, 256, 0, stream>>>(z, cb, cnorm, flist, fcnt, prd, pri);
    rsmerge_kernel<<<N_TOK / 256, 256, 0, stream>>>(prd, pri, flist, fcnt, ws_idx, out_idx);

    // partials are dead now; reuse region A as the embed-sum accumulator
    hipMemsetAsync(w + OFF_EMBED, 0, (size_t)KCODE * DDIM * sizeof(float), stream);

    gather_scatter_kernel<<<N_TOK * 64 / 256, 256, 0, stream>>>(z, cb, ws_idx, out_q, embed, counts, sumsq);
    cluster_kernel<<<(KCODE + 255) / 256, 256, 0, stream>>>(ema_cs, counts, out_ncs, n_acc, sumsq, out_loss);
    codebook_kernel<<<(KCODE * DDIM) / 256, 256, 0, stream>>>(ema_es, embed, out_ncs, n_acc, out_es, out_cb);
}